// Round 11
// baseline (304.735 us; speedup 1.0000x reference)
//
#include <hip/hip_runtime.h>
#include <hip/hip_bf16.h>

typedef unsigned int   u32;
typedef unsigned short u16;
typedef unsigned char  u8;
typedef float f32x2 __attribute__((ext_vector_type(2)));

#define N_NODES 50000
#define C_DIM   128
#define E_EDGES 1600000
#define NUM_IDX 2048

#define CPB 256                    // cols per coarse bucket (key >> 8)
#define NB  196                    // ceil(N/CPB)
#define CHK 4096                   // edges per chunk
#define NP  391                    // ceil(E/CHK)
#define PT  512                    // threads for partition-family kernels
#define NLB 98                     // label blocks: ceil(N/512)
#define NBLK 32                    // nodes per node_msg block
#define NMB ((N_NODES + NBLK - 1) / NBLK)   // 1563

// K1 (fused): blocks [0,NP) = per-chunk coarse histograms (col,row) -> Hc,Hr;
//             blocks [NP,NP+NLB) = label histogram + id histogram.
__global__ __launch_bounds__(PT) void hist_all_kernel(
        const int* __restrict__ row, const int* __restrict__ col,
        int* __restrict__ Hc, int* __restrict__ Hr,
        const int* __restrict__ label, int* __restrict__ labCnt,
        const int* __restrict__ id, int* __restrict__ cnt) {
    int t = threadIdx.x;
    if (blockIdx.x >= NP) {
        __shared__ int h[8];
        if (t < 8) h[t] = 0;
        __syncthreads();
        int n = (blockIdx.x - NP) * PT + t;
        if (n < N_NODES) atomicAdd(&h[label[n]], 1);
        if (n < NUM_IDX) atomicAdd(&cnt[id[n]], 1);
        __syncthreads();
        if (t < 8 && h[t] > 0) atomicAdd(&labCnt[t], h[t]);
        return;
    }
    __shared__ int hc[NB], hr[NB];
    int p = blockIdx.x;
    for (int i = t; i < NB; i += PT) { hc[i] = 0; hr[i] = 0; }
    __syncthreads();
    int e0 = p * CHK, e1 = min(e0 + CHK, E_EDGES);
    for (int e = e0 + t; e < e1; e += PT) {
        atomicAdd(&hc[col[e] >> 8], 1);
        atomicAdd(&hr[row[e] >> 8], 1);
    }
    __syncthreads();
    for (int i = t; i < NB; i += PT) {
        Hc[p * NB + i] = hc[i];
        Hr[p * NB + i] = hr[i];
    }
}

// K2: per-bucket scan across chunks: H[p][j] -> exclusive prefix (in place), tot[j].
__global__ __launch_bounds__(PT) void offsets_kernel(
        int* __restrict__ Hc, int* __restrict__ Hr,
        int* __restrict__ colTot, int* __restrict__ rowTot) {
    __shared__ int sc[PT];
    int b = blockIdx.x;
    int j = (b < NB) ? b : b - NB;
    int* H   = (b < NB) ? Hc : Hr;
    int* tot = (b < NB) ? colTot : rowTot;
    int t = threadIdx.x;
    int v = (t < NP) ? H[t * NB + j] : 0;
    sc[t] = v;
    __syncthreads();
    for (int off = 1; off < PT; off <<= 1) {
        int a = (t >= off) ? sc[t - off] : 0;
        int s = sc[t];
        __syncthreads();
        sc[t] = s + a;
        __syncthreads();
    }
    if (t < NP) H[t * NB + j] = sc[t] - v;
    if (t == PT - 1) tot[j] = sc[t];
}

// K3: scan bucket totals -> bucketStart/rowStart; labCnt -> labCur bases.
__global__ void bucket_scan_kernel(const int* __restrict__ colTot, const int* __restrict__ rowTot,
                                   int* __restrict__ bucketStart, int* __restrict__ rowStart,
                                   const int* __restrict__ labCnt, int* __restrict__ labCur) {
    __shared__ int sc[256];
    int t = threadIdx.x;
    sc[t] = (t < NB) ? colTot[t] : 0;
    __syncthreads();
    for (int off = 1; off < 256; off <<= 1) {
        int v = sc[t];
        int a = (t >= off) ? sc[t - off] : 0;
        __syncthreads();
        sc[t] = v + a;
        __syncthreads();
    }
    if (t < NB) {
        bucketStart[t] = (t == 0) ? 0 : sc[t - 1];
        if (t == NB - 1) bucketStart[NB] = sc[t];
    }
    __syncthreads();
    sc[t] = (t < NB) ? rowTot[t] : 0;
    __syncthreads();
    for (int off = 1; off < 256; off <<= 1) {
        int v = sc[t];
        int a = (t >= off) ? sc[t - off] : 0;
        __syncthreads();
        sc[t] = v + a;
        __syncthreads();
    }
    if (t < NB) {
        rowStart[t] = (t == 0) ? 0 : sc[t - 1];
        if (t == NB - 1) rowStart[NB] = sc[t];
    }
    if (t == 0) {
        int run = 0;
        for (int i = 0; i < 8; ++i) { labCur[i] = run; run += labCnt[i]; }
    }
}

// K4 (fused): blocks [0,NP) = partition edges into S (packed (row<<8)|(col&255)) + Sr;
//             blocks [NP,NP+NLB) = compact nodes grouped by label.
__global__ __launch_bounds__(PT) void part_fill_kernel(
        const int* __restrict__ row, const int* __restrict__ col,
        const int* __restrict__ Hc, const int* __restrict__ Hr,
        const int* __restrict__ bucketStart, const int* __restrict__ rowStart,
        u32* __restrict__ S, u8* __restrict__ Sr,
        const int* __restrict__ label, int* __restrict__ labCur,
        int* __restrict__ nodeByLabel) {
    int t = threadIdx.x;
    if (blockIdx.x >= NP) {
        __shared__ int h8[8], base8[8], c28[8];
        if (t < 8) { h8[t] = 0; c28[t] = 0; }
        __syncthreads();
        int n = (blockIdx.x - NP) * PT + t;
        int l = 0;
        if (n < N_NODES) { l = label[n]; atomicAdd(&h8[l], 1); }
        __syncthreads();
        if (t < 8 && h8[t] > 0) base8[t] = atomicAdd(&labCur[t], h8[t]);
        __syncthreads();
        if (n < N_NODES) {
            int pos = base8[l] + atomicAdd(&c28[l], 1);
            nodeByLabel[pos] = n;
        }
        return;
    }
    __shared__ int bc_[NB], br_[NB];
    int p = blockIdx.x;
    for (int i = t; i < NB; i += PT) {
        bc_[i] = bucketStart[i] + Hc[p * NB + i];
        br_[i] = rowStart[i]   + Hr[p * NB + i];
    }
    __syncthreads();
    int e0 = p * CHK, e1 = min(e0 + CHK, E_EDGES);
    for (int e = e0 + t; e < e1; e += PT) {
        int r = row[e], c = col[e];
        int pc = atomicAdd(&bc_[c >> 8], 1);
        S[pc] = ((u32)r << 8) | (u32)(c & 255);
        int pr = atomicAdd(&br_[r >> 8], 1);
        Sr[pr] = (u8)(r & 255);
    }
}

// K5 (fused): blocks [0,NB) = fine CSR (start[] + srcrow u16);
//             blocks [NB,2NB) = degree -> dinv.
__global__ __launch_bounds__(PT) void csr_deg_kernel(
        const u32* __restrict__ S, const u8* __restrict__ Sr,
        const int* __restrict__ bucketStart, const int* __restrict__ rowStart,
        int* __restrict__ start, u16* __restrict__ srcrow,
        float* __restrict__ dinv) {
    __shared__ int h[CPB], cur[CPB], sc[CPB];
    int t = threadIdx.x;
    if (blockIdx.x >= NB) {
        int b = blockIdx.x - NB;
        if (t < CPB) h[t] = 0;
        __syncthreads();
        int e0 = rowStart[b], e1 = rowStart[b + 1];
        for (int e = e0 + t; e < e1; e += PT) atomicAdd(&h[Sr[e]], 1);
        __syncthreads();
        if (t < CPB) {
            int n = b * CPB + t;
            if (n < N_NODES) dinv[n] = rsqrtf((float)(h[t] + 1));
        }
        return;
    }
    int b = blockIdx.x;
    if (t < CPB) h[t] = 0;
    __syncthreads();
    int e0 = bucketStart[b], e1 = bucketStart[b + 1];
    for (int e = e0 + t; e < e1; e += PT) atomicAdd(&h[S[e] & 255u], 1);
    __syncthreads();
    if (t < CPB) sc[t] = h[t];
    __syncthreads();
    for (int off = 1; off < CPB; off <<= 1) {
        int v = 0, a = 0;
        if (t < CPB) { v = sc[t]; a = (t >= off) ? sc[t - off] : 0; }
        __syncthreads();
        if (t < CPB) sc[t] = v + a;
        __syncthreads();
    }
    if (t < CPB) {
        int base = (t == 0) ? 0 : sc[t - 1];
        int gcol = b * CPB + t;
        if (gcol < N_NODES) start[gcol] = e0 + base;
        cur[t] = base;
    }
    if (b == NB - 1 && t == 0) start[N_NODES] = E_EDGES;
    __syncthreads();
    for (int e = e0 + t; e < e1; e += PT) {
        u32 v = S[e];
        int pos = atomicAdd(&cur[v & 255u], 1);
        srcrow[e0 + pos] = (u16)(v >> 8);
    }
}

// K6: node transform, W-in-LDS. Block = 256 threads (s = t>>7 node half, c = t&127),
// 32 label-sorted nodes; weight staged in LDS in two 32KB halves; acc[16] in VGPRs.
__global__ __launch_bounds__(256) void node_msg_kernel(
        const float* __restrict__ x, const int* __restrict__ cnt,
        const int* __restrict__ label, const float* __restrict__ dinv,
        const float* __restrict__ W, const float* __restrict__ Wid,
        const int* __restrict__ nodeByLabel, __hip_bfloat16* __restrict__ msgb) {
    __shared__ float Wl[64 * C_DIM];        // 32 KB: half of the 128x128 weight
    __shared__ float xs[NBLK * C_DIM];      // 16 KB
    __shared__ int nid[NBLK], lab[NBLK], cc[NBLK];
    int t = threadIdx.x;
    int s = t >> 7, c = t & 127;
    int base = blockIdx.x * NBLK;
    int nb = min(NBLK, N_NODES - base);
    if (t < nb) {
        int n = nodeByLabel[base + t];
        nid[t] = n; lab[t] = label[n]; cc[t] = cnt[n];
    }
    __syncthreads();
    // stage x rows (float4-coalesced)
    for (int idx = t; idx < nb * 32; idx += 256) {
        int g = idx >> 5, c4 = (idx & 31) << 2;
        *(float4*)&xs[g * C_DIM + c4] =
            *(const float4*)&x[(size_t)nid[g] * C_DIM + c4];
    }
    __syncthreads();
    // ego update (~1-2 nodes/block): x1 = x + cnt*(x@W), W from global (L2-resident)
    for (int g = 0; g < nb; ++g) {
        int cg = cc[g];
        if (cg > 0) {                        // block-uniform branch
            float acc = 0.f;
            #pragma unroll 8
            for (int k = 0; k < C_DIM; ++k)
                acc += xs[g * C_DIM + k] * W[k * C_DIM + c];
            __syncthreads();
            if (s == 0) xs[g * C_DIM + c] += (float)cg * acc;
            __syncthreads();
        }
    }
    int L0 = lab[0], L1 = lab[nb - 1];
    if (L0 == L1 && L0 > 0) {
        // uniform non-zero label: staged-W matmul
        const float* Wg = Wid + (size_t)(L0 - 1) * C_DIM * C_DIM;
        float acc[16];
        #pragma unroll
        for (int g = 0; g < 16; ++g) acc[g] = 0.f;
        int gbase = s * 16;
        int gcnt = nb - gbase; if (gcnt < 0) gcnt = 0; if (gcnt > 16) gcnt = 16;
        // phase A: k in [0,64)
        for (int i = t; i < 64 * 32; i += 256) {
            int kk = i >> 5, c4 = (i & 31) << 2;
            *(float4*)&Wl[kk * C_DIM + c4] = *(const float4*)&Wg[kk * C_DIM + c4];
        }
        __syncthreads();
        for (int k = 0; k < 64; k += 4) {
            float w0 = Wl[k * C_DIM + c],       w1 = Wl[(k + 1) * C_DIM + c];
            float w2 = Wl[(k + 2) * C_DIM + c], w3 = Wl[(k + 3) * C_DIM + c];
            #pragma unroll
            for (int g = 0; g < 16; ++g) {
                float4 xv = *(const float4*)&xs[(gbase + g) * C_DIM + k];
                acc[g] += w0 * xv.x + w1 * xv.y + w2 * xv.z + w3 * xv.w;
            }
        }
        __syncthreads();
        // phase B: k in [64,128)
        for (int i = t; i < 64 * 32; i += 256) {
            int kk = i >> 5, c4 = (i & 31) << 2;
            *(float4*)&Wl[kk * C_DIM + c4] = *(const float4*)&Wg[(64 + kk) * C_DIM + c4];
        }
        __syncthreads();
        for (int k = 0; k < 64; k += 4) {
            float w0 = Wl[k * C_DIM + c],       w1 = Wl[(k + 1) * C_DIM + c];
            float w2 = Wl[(k + 2) * C_DIM + c], w3 = Wl[(k + 3) * C_DIM + c];
            #pragma unroll
            for (int g = 0; g < 16; ++g) {
                float4 xv = *(const float4*)&xs[(gbase + g) * C_DIM + 64 + k];
                acc[g] += w0 * xv.x + w1 * xv.y + w2 * xv.z + w3 * xv.w;
            }
        }
        for (int g = 0; g < gcnt; ++g) {
            int n = nid[gbase + g];
            msgb[(size_t)n * C_DIM + c] =
                __float2bfloat16(dinv[n] * (xs[(gbase + g) * C_DIM + c] + acc[g]));
        }
    } else if (L0 == L1) {
        // uniform label 0: passthrough
        int gbase = s * 16;
        int gcnt = nb - gbase; if (gcnt < 0) gcnt = 0; if (gcnt > 16) gcnt = 16;
        for (int g = 0; g < gcnt; ++g) {
            int n = nid[gbase + g];
            msgb[(size_t)n * C_DIM + c] =
                __float2bfloat16(dinv[n] * xs[(gbase + g) * C_DIM + c]);
        }
    } else {
        // straddle block (<=7 total): per-node fallback with global W reads
        for (int g = 0; g < nb; ++g) {
            int L = lab[g];
            float res = xs[g * C_DIM + c];
            if (L > 0) {
                const float* Wg = Wid + (size_t)(L - 1) * C_DIM * C_DIM;
                float acc = 0.f;
                #pragma unroll 8
                for (int k = 0; k < C_DIM; ++k)
                    acc += xs[g * C_DIM + k] * Wg[k * C_DIM + c];
                res += acc;
            }
            if (s == 0) {
                int n = nid[g];
                msgb[(size_t)n * C_DIM + c] = __float2bfloat16(dinv[n] * res);
            }
        }
    }
}

// K7: gather + finalize. One wave per dest node; lane owns a bf16 channel pair.
__global__ void gather_kernel(const int* __restrict__ start,
                              const u16* __restrict__ srcrow,
                              const float* __restrict__ dinv,
                              const u32* __restrict__ m32,   // bf16x2-packed msg
                              float* __restrict__ out) {
    int wid  = threadIdx.x >> 6;
    int lane = threadIdx.x & 63;
    int c = blockIdx.x * 4 + wid;
    int e0 = start[c], e1 = start[c + 1];
    u32 u = m32[((u32)c << 6) | lane];                       // self-loop message
    float a0 = __uint_as_float(u << 16);
    float a1 = __uint_as_float(u & 0xffff0000u);
    int e = e0;
    for (; e + 8 <= e1; e += 8) {
        u32 rr[8], uu[8];
        #pragma unroll
        for (int j = 0; j < 8; ++j) rr[j] = srcrow[e + j];
        #pragma unroll
        for (int j = 0; j < 8; ++j) uu[j] = m32[(rr[j] << 6) | (u32)lane];
        #pragma unroll
        for (int j = 0; j < 8; ++j) {
            a0 += __uint_as_float(uu[j] << 16);
            a1 += __uint_as_float(uu[j] & 0xffff0000u);
        }
    }
    for (; e < e1; ++e) {
        u32 ue = m32[((u32)srcrow[e] << 6) | (u32)lane];
        a0 += __uint_as_float(ue << 16);
        a1 += __uint_as_float(ue & 0xffff0000u);
    }
    float di = dinv[c];
    f32x2 o; o.x = di * a0; o.y = di * a1;
    __builtin_nontemporal_store(o, (f32x2*)out + (((u32)c << 6) | lane));
}

extern "C" void kernel_launch(void* const* d_in, const int* in_sizes, int n_in,
                              void* d_out, int out_size, void* d_ws, size_t ws_size,
                              hipStream_t stream) {
    const float* x     = (const float*)d_in[0];
    const int*   edge  = (const int*)d_in[1];   // [2][E]
    const int*   id    = (const int*)d_in[2];
    const int*   label = (const int*)d_in[3];
    const float* W     = (const float*)d_in[4];
    const float* Wid   = (const float*)d_in[5];
    float*       out   = (float*)d_out;

    const int* row = edge;
    const int* col = edge + E_EDGES;

    // ws layout:
    // msgb[N*C] bf16 | S[E] u32 | srcrow[E] u16 | Sr[E] u8 | start[N+1] |
    // bucketStart[NB+1] | rowStart[NB+1] | Hc[NP*NB] | Hr[NP*NB] | colTot[NB] | rowTot[NB] |
    // nodeByLabel[N] | dinv[N] f32 | ZERO{ cnt[N] | labCnt[8] | labCur[8] }
    __hip_bfloat16* msgb = (__hip_bfloat16*)d_ws;
    u32* S           = (u32*)(msgb + (size_t)N_NODES * C_DIM);
    u16* srcrow      = (u16*)(S + E_EDGES);
    u8*  Sr          = (u8*)(srcrow + E_EDGES);
    int* start       = (int*)(Sr + E_EDGES);
    int* bucketStart = start + (N_NODES + 1);
    int* rowStart    = bucketStart + (NB + 1);
    int* Hc          = rowStart + (NB + 1);
    int* Hr          = Hc + NP * NB;
    int* colTot      = Hr + NP * NB;
    int* rowTot      = colTot + NB;
    int* nodeByLabel = rowTot + NB;
    float* dinv      = (float*)(nodeByLabel + N_NODES);
    int* cnt         = (int*)(dinv + N_NODES);
    int* labCnt      = cnt + N_NODES;
    int* labCur      = labCnt + 8;

    hipMemsetAsync(cnt, 0, ((size_t)N_NODES + 16) * sizeof(int), stream);

    hist_all_kernel   <<<NP + NLB, PT, 0, stream>>>(row, col, Hc, Hr,
                                                    label, labCnt, id, cnt);
    offsets_kernel    <<<2 * NB, PT, 0, stream>>>(Hc, Hr, colTot, rowTot);
    bucket_scan_kernel<<<1, 256, 0, stream>>>(colTot, rowTot, bucketStart, rowStart,
                                              labCnt, labCur);
    part_fill_kernel  <<<NP + NLB, PT, 0, stream>>>(row, col, Hc, Hr, bucketStart, rowStart,
                                                    S, Sr, label, labCur, nodeByLabel);
    csr_deg_kernel    <<<2 * NB, PT, 0, stream>>>(S, Sr, bucketStart, rowStart,
                                                  start, srcrow, dinv);
    node_msg_kernel   <<<NMB, 256, 0, stream>>>(x, cnt, label, dinv, W, Wid,
                                                nodeByLabel, msgb);
    gather_kernel     <<<N_NODES / 4, 256, 0, stream>>>(start, srcrow, dinv,
                                                        (const u32*)msgb, out);
}

// Round 12
// 244.713 us; speedup vs baseline: 1.2453x; 1.2453x over previous
//
#include <hip/hip_runtime.h>
#include <hip/hip_bf16.h>

typedef unsigned int   u32;
typedef unsigned short u16;
typedef unsigned char  u8;
typedef float f32x2 __attribute__((ext_vector_type(2)));

#define N_NODES 50000
#define C_DIM   128
#define E_EDGES 1600000
#define NUM_IDX 2048

#define CPB 256                    // cols per coarse bucket (key >> 8)
#define NB  196                    // ceil(N/CPB)
#define CHK 4096                   // edges per chunk
#define NP  391                    // ceil(E/CHK)
#define PT  512                    // threads for partition-family kernels
#define NLB 98                     // label blocks: ceil(N/512)
#define GB  8                      // nodes per node_msg block (r8-proven)

// K1 (fused): blocks [0,NP) = per-chunk coarse histograms (col,row) -> Hc,Hr;
//             blocks [NP,NP+NLB) = label histogram + id histogram.
__global__ __launch_bounds__(PT) void hist_all_kernel(
        const int* __restrict__ row, const int* __restrict__ col,
        int* __restrict__ Hc, int* __restrict__ Hr,
        const int* __restrict__ label, int* __restrict__ labCnt,
        const int* __restrict__ id, int* __restrict__ cnt) {
    int t = threadIdx.x;
    if (blockIdx.x >= NP) {
        __shared__ int h[8];
        if (t < 8) h[t] = 0;
        __syncthreads();
        int n = (blockIdx.x - NP) * PT + t;
        if (n < N_NODES) atomicAdd(&h[label[n]], 1);
        if (n < NUM_IDX) atomicAdd(&cnt[id[n]], 1);
        __syncthreads();
        if (t < 8 && h[t] > 0) atomicAdd(&labCnt[t], h[t]);
        return;
    }
    __shared__ int hc[NB], hr[NB];
    int p = blockIdx.x;
    for (int i = t; i < NB; i += PT) { hc[i] = 0; hr[i] = 0; }
    __syncthreads();
    int e0 = p * CHK, e1 = min(e0 + CHK, E_EDGES);
    for (int e = e0 + t; e < e1; e += PT) {
        atomicAdd(&hc[col[e] >> 8], 1);
        atomicAdd(&hr[row[e] >> 8], 1);
    }
    __syncthreads();
    for (int i = t; i < NB; i += PT) {
        Hc[p * NB + i] = hc[i];
        Hr[p * NB + i] = hr[i];
    }
}

// K2: per-bucket scan across chunks: H[p][j] -> exclusive prefix (in place), tot[j].
__global__ __launch_bounds__(PT) void offsets_kernel(
        int* __restrict__ Hc, int* __restrict__ Hr,
        int* __restrict__ colTot, int* __restrict__ rowTot) {
    __shared__ int sc[PT];
    int b = blockIdx.x;
    int j = (b < NB) ? b : b - NB;
    int* H   = (b < NB) ? Hc : Hr;
    int* tot = (b < NB) ? colTot : rowTot;
    int t = threadIdx.x;
    int v = (t < NP) ? H[t * NB + j] : 0;
    sc[t] = v;
    __syncthreads();
    for (int off = 1; off < PT; off <<= 1) {
        int a = (t >= off) ? sc[t - off] : 0;
        int s = sc[t];
        __syncthreads();
        sc[t] = s + a;
        __syncthreads();
    }
    if (t < NP) H[t * NB + j] = sc[t] - v;
    if (t == PT - 1) tot[j] = sc[t];
}

// K3: scan bucket totals -> bucketStart/rowStart; labCnt -> labCur bases.
__global__ void bucket_scan_kernel(const int* __restrict__ colTot, const int* __restrict__ rowTot,
                                   int* __restrict__ bucketStart, int* __restrict__ rowStart,
                                   const int* __restrict__ labCnt, int* __restrict__ labCur) {
    __shared__ int sc[256];
    int t = threadIdx.x;
    sc[t] = (t < NB) ? colTot[t] : 0;
    __syncthreads();
    for (int off = 1; off < 256; off <<= 1) {
        int v = sc[t];
        int a = (t >= off) ? sc[t - off] : 0;
        __syncthreads();
        sc[t] = v + a;
        __syncthreads();
    }
    if (t < NB) {
        bucketStart[t] = (t == 0) ? 0 : sc[t - 1];
        if (t == NB - 1) bucketStart[NB] = sc[t];
    }
    __syncthreads();
    sc[t] = (t < NB) ? rowTot[t] : 0;
    __syncthreads();
    for (int off = 1; off < 256; off <<= 1) {
        int v = sc[t];
        int a = (t >= off) ? sc[t - off] : 0;
        __syncthreads();
        sc[t] = v + a;
        __syncthreads();
    }
    if (t < NB) {
        rowStart[t] = (t == 0) ? 0 : sc[t - 1];
        if (t == NB - 1) rowStart[NB] = sc[t];
    }
    if (t == 0) {
        int run = 0;
        for (int i = 0; i < 8; ++i) { labCur[i] = run; run += labCnt[i]; }
    }
}

// K4 (fused): blocks [0,NP) = partition edges into S (packed (row<<8)|(col&255)) + Sr;
//             blocks [NP,NP+NLB) = compact nodes grouped by label.
__global__ __launch_bounds__(PT) void part_fill_kernel(
        const int* __restrict__ row, const int* __restrict__ col,
        const int* __restrict__ Hc, const int* __restrict__ Hr,
        const int* __restrict__ bucketStart, const int* __restrict__ rowStart,
        u32* __restrict__ S, u8* __restrict__ Sr,
        const int* __restrict__ label, int* __restrict__ labCur,
        int* __restrict__ nodeByLabel) {
    int t = threadIdx.x;
    if (blockIdx.x >= NP) {
        __shared__ int h8[8], base8[8], c28[8];
        if (t < 8) { h8[t] = 0; c28[t] = 0; }
        __syncthreads();
        int n = (blockIdx.x - NP) * PT + t;
        int l = 0;
        if (n < N_NODES) { l = label[n]; atomicAdd(&h8[l], 1); }
        __syncthreads();
        if (t < 8 && h8[t] > 0) base8[t] = atomicAdd(&labCur[t], h8[t]);
        __syncthreads();
        if (n < N_NODES) {
            int pos = base8[l] + atomicAdd(&c28[l], 1);
            nodeByLabel[pos] = n;
        }
        return;
    }
    __shared__ int bc_[NB], br_[NB];
    int p = blockIdx.x;
    for (int i = t; i < NB; i += PT) {
        bc_[i] = bucketStart[i] + Hc[p * NB + i];
        br_[i] = rowStart[i]   + Hr[p * NB + i];
    }
    __syncthreads();
    int e0 = p * CHK, e1 = min(e0 + CHK, E_EDGES);
    for (int e = e0 + t; e < e1; e += PT) {
        int r = row[e], c = col[e];
        int pc = atomicAdd(&bc_[c >> 8], 1);
        S[pc] = ((u32)r << 8) | (u32)(c & 255);
        int pr = atomicAdd(&br_[r >> 8], 1);
        Sr[pr] = (u8)(r & 255);
    }
}

// K5 (fused): blocks [0,NB) = fine CSR (start[] + srcrow u16);
//             blocks [NB,2NB) = degree -> dinv.
__global__ __launch_bounds__(PT) void csr_deg_kernel(
        const u32* __restrict__ S, const u8* __restrict__ Sr,
        const int* __restrict__ bucketStart, const int* __restrict__ rowStart,
        int* __restrict__ start, u16* __restrict__ srcrow,
        float* __restrict__ dinv) {
    __shared__ int h[CPB], cur[CPB], sc[CPB];
    int t = threadIdx.x;
    if (blockIdx.x >= NB) {
        int b = blockIdx.x - NB;
        if (t < CPB) h[t] = 0;
        __syncthreads();
        int e0 = rowStart[b], e1 = rowStart[b + 1];
        for (int e = e0 + t; e < e1; e += PT) atomicAdd(&h[Sr[e]], 1);
        __syncthreads();
        if (t < CPB) {
            int n = b * CPB + t;
            if (n < N_NODES) dinv[n] = rsqrtf((float)(h[t] + 1));
        }
        return;
    }
    int b = blockIdx.x;
    if (t < CPB) h[t] = 0;
    __syncthreads();
    int e0 = bucketStart[b], e1 = bucketStart[b + 1];
    for (int e = e0 + t; e < e1; e += PT) atomicAdd(&h[S[e] & 255u], 1);
    __syncthreads();
    if (t < CPB) sc[t] = h[t];
    __syncthreads();
    for (int off = 1; off < CPB; off <<= 1) {
        int v = 0, a = 0;
        if (t < CPB) { v = sc[t]; a = (t >= off) ? sc[t - off] : 0; }
        __syncthreads();
        if (t < CPB) sc[t] = v + a;
        __syncthreads();
    }
    if (t < CPB) {
        int base = (t == 0) ? 0 : sc[t - 1];
        int gcol = b * CPB + t;
        if (gcol < N_NODES) start[gcol] = e0 + base;
        cur[t] = base;
    }
    if (b == NB - 1 && t == 0) start[N_NODES] = E_EDGES;
    __syncthreads();
    for (int e = e0 + t; e < e1; e += PT) {
        u32 v = S[e];
        int pos = atomicAdd(&cur[v & 255u], 1);
        srcrow[e0 + pos] = (u16)(v >> 8);
    }
}

// K6: label-grouped node transform -> bf16 messages (GB=8, r8-proven structure,
// with float4 xs broadcasts + k-unroll-4).
__global__ void node_msg_kernel(const float* __restrict__ x,
                                const int* __restrict__ cnt,
                                const int* __restrict__ label,
                                const float* __restrict__ dinv,
                                const float* __restrict__ W,
                                const float* __restrict__ Wid,
                                const int* __restrict__ nodeByLabel,
                                __hip_bfloat16* __restrict__ msgb) {
    __shared__ float xs[GB][C_DIM];
    __shared__ int nid[GB], lab[GB], cc[GB];
    int t = threadIdx.x;
    if (t < GB) {
        int n = nodeByLabel[blockIdx.x * GB + t];
        nid[t] = n; lab[t] = label[n]; cc[t] = cnt[n];
    }
    __syncthreads();
    #pragma unroll
    for (int g = 0; g < GB; ++g)
        xs[g][t] = __builtin_nontemporal_load(x + (size_t)nid[g] * C_DIM + t);
    __syncthreads();
    for (int g = 0; g < GB; ++g) {          // ego update (~4% of nodes)
        int c = cc[g];
        if (c > 0) {                        // block-uniform branch
            float acc = 0.f;
            #pragma unroll 8
            for (int k = 0; k < C_DIM; ++k) acc += xs[g][k] * W[k * C_DIM + t];
            __syncthreads();
            xs[g][t] += (float)c * acc;
            __syncthreads();
        }
    }
    float res[GB];
    #pragma unroll
    for (int g = 0; g < GB; ++g) res[g] = xs[g][t];
    if (lab[0] == lab[GB - 1]) {
        int L = lab[0];
        if (L > 0) {
            const float* Wl = Wid + (size_t)(L - 1) * C_DIM * C_DIM;
            float acc[GB];
            #pragma unroll
            for (int g = 0; g < GB; ++g) acc[g] = 0.f;
            for (int k = 0; k < C_DIM; k += 4) {
                float w0 = Wl[k * C_DIM + t];
                float w1 = Wl[(k + 1) * C_DIM + t];
                float w2 = Wl[(k + 2) * C_DIM + t];
                float w3 = Wl[(k + 3) * C_DIM + t];
                #pragma unroll
                for (int g = 0; g < GB; ++g) {
                    float4 xv = *(const float4*)&xs[g][k];
                    acc[g] += w0 * xv.x + w1 * xv.y + w2 * xv.z + w3 * xv.w;
                }
            }
            #pragma unroll
            for (int g = 0; g < GB; ++g) res[g] += acc[g];
        }
    } else {
        // straddle block (<=7 total): per-node fallback
        for (int g = 0; g < GB; ++g) {
            int L = lab[g];
            if (L > 0) {
                const float* Wl = Wid + (size_t)(L - 1) * C_DIM * C_DIM;
                float acc = 0.f;
                #pragma unroll 8
                for (int k = 0; k < C_DIM; ++k) acc += xs[g][k] * Wl[k * C_DIM + t];
                res[g] += acc;
            }
        }
    }
    #pragma unroll
    for (int g = 0; g < GB; ++g) {
        int n = nid[g];
        msgb[(size_t)n * C_DIM + t] = __float2bfloat16(dinv[n] * res[g]);
    }
}

// K7: gather + finalize. One wave per dest node; lane owns a bf16 channel pair.
__global__ void gather_kernel(const int* __restrict__ start,
                              const u16* __restrict__ srcrow,
                              const float* __restrict__ dinv,
                              const u32* __restrict__ m32,   // bf16x2-packed msg
                              float* __restrict__ out) {
    int wid  = threadIdx.x >> 6;
    int lane = threadIdx.x & 63;
    int c = blockIdx.x * 4 + wid;
    int e0 = start[c], e1 = start[c + 1];
    u32 u = m32[((u32)c << 6) | lane];                       // self-loop message
    float a0 = __uint_as_float(u << 16);
    float a1 = __uint_as_float(u & 0xffff0000u);
    int e = e0;
    for (; e + 8 <= e1; e += 8) {
        u32 rr[8], uu[8];
        #pragma unroll
        for (int j = 0; j < 8; ++j) rr[j] = srcrow[e + j];
        #pragma unroll
        for (int j = 0; j < 8; ++j) uu[j] = m32[(rr[j] << 6) | (u32)lane];
        #pragma unroll
        for (int j = 0; j < 8; ++j) {
            a0 += __uint_as_float(uu[j] << 16);
            a1 += __uint_as_float(uu[j] & 0xffff0000u);
        }
    }
    for (; e < e1; ++e) {
        u32 ue = m32[((u32)srcrow[e] << 6) | (u32)lane];
        a0 += __uint_as_float(ue << 16);
        a1 += __uint_as_float(ue & 0xffff0000u);
    }
    float di = dinv[c];
    f32x2 o; o.x = di * a0; o.y = di * a1;
    __builtin_nontemporal_store(o, (f32x2*)out + (((u32)c << 6) | lane));
}

extern "C" void kernel_launch(void* const* d_in, const int* in_sizes, int n_in,
                              void* d_out, int out_size, void* d_ws, size_t ws_size,
                              hipStream_t stream) {
    const float* x     = (const float*)d_in[0];
    const int*   edge  = (const int*)d_in[1];   // [2][E]
    const int*   id    = (const int*)d_in[2];
    const int*   label = (const int*)d_in[3];
    const float* W     = (const float*)d_in[4];
    const float* Wid   = (const float*)d_in[5];
    float*       out   = (float*)d_out;

    const int* row = edge;
    const int* col = edge + E_EDGES;

    // ws layout:
    // msgb[N*C] bf16 | S[E] u32 | srcrow[E] u16 | Sr[E] u8 | start[N+1] |
    // bucketStart[NB+1] | rowStart[NB+1] | Hc[NP*NB] | Hr[NP*NB] | colTot[NB] | rowTot[NB] |
    // nodeByLabel[N] | dinv[N] f32 | ZERO{ cnt[N] | labCnt[8] | labCur[8] }
    __hip_bfloat16* msgb = (__hip_bfloat16*)d_ws;
    u32* S           = (u32*)(msgb + (size_t)N_NODES * C_DIM);
    u16* srcrow      = (u16*)(S + E_EDGES);
    u8*  Sr          = (u8*)(srcrow + E_EDGES);
    int* start       = (int*)(Sr + E_EDGES);
    int* bucketStart = start + (N_NODES + 1);
    int* rowStart    = bucketStart + (NB + 1);
    int* Hc          = rowStart + (NB + 1);
    int* Hr          = Hc + NP * NB;
    int* colTot      = Hr + NP * NB;
    int* rowTot      = colTot + NB;
    int* nodeByLabel = rowTot + NB;
    float* dinv      = (float*)(nodeByLabel + N_NODES);
    int* cnt         = (int*)(dinv + N_NODES);
    int* labCnt      = cnt + N_NODES;
    int* labCur      = labCnt + 8;

    hipMemsetAsync(cnt, 0, ((size_t)N_NODES + 16) * sizeof(int), stream);

    hist_all_kernel   <<<NP + NLB, PT, 0, stream>>>(row, col, Hc, Hr,
                                                    label, labCnt, id, cnt);
    offsets_kernel    <<<2 * NB, PT, 0, stream>>>(Hc, Hr, colTot, rowTot);
    bucket_scan_kernel<<<1, 256, 0, stream>>>(colTot, rowTot, bucketStart, rowStart,
                                              labCnt, labCur);
    part_fill_kernel  <<<NP + NLB, PT, 0, stream>>>(row, col, Hc, Hr, bucketStart, rowStart,
                                                    S, Sr, label, labCur, nodeByLabel);
    csr_deg_kernel    <<<2 * NB, PT, 0, stream>>>(S, Sr, bucketStart, rowStart,
                                                  start, srcrow, dinv);
    node_msg_kernel   <<<N_NODES / GB, C_DIM, 0, stream>>>(x, cnt, label, dinv, W, Wid,
                                                           nodeByLabel, msgb);
    gather_kernel     <<<N_NODES / 4, 256, 0, stream>>>(start, srcrow, dinv,
                                                        (const u32*)msgb, out);
}